// Round 18
// baseline (107.476 us; speedup 1.0000x reference)
//
#include <hip/hip_runtime.h>
#include <hip/hip_fp16.h>

#define NN 50000
#define NE 800000
#define FIN 128
#define NH 4
#define HD 32
#define FOUT 128   // NH*HD
#define NEG 0.2f
#define NB_W    ((256 * FIN + 255) / 256) // 128
#define N_GEMM  782                  // 64-row stripes; each block does all 4 col-tiles
#define NBKT    98                   // dst>>9 buckets (512 nodes each)
#define CHUNK   4096                 // edges per hist/scatter chunk
#define NCHUNK  ((NE + CHUNK - 1) / CHUNK)  // 196
#define BCAP    12288                // binB LDS segment capacity (mean 8163, max ~8600)

typedef __attribute__((ext_vector_type(8))) short bf16x8;
typedef __attribute__((ext_vector_type(4))) float f32x4;

__device__ __forceinline__ uint f2bf_u(float f) {
    uint u = __float_as_uint(f);
    u += 0x7FFF + ((u >> 16) & 1);   // round-to-nearest-even
    return u >> 16;
}
__device__ __forceinline__ ushort f2bf(float f) { return (ushort)f2bf_u(f); }
__device__ __forceinline__ uint f2h_u(float f) {
    return (uint)__builtin_bit_cast(ushort, __float2half(f));
}

template<int CTRL>
__device__ __forceinline__ float dpp_add(float x) {
    int y = __builtin_amdgcn_update_dpp(0, __float_as_int(x), CTRL, 0xF, 0xF, false);
    return x + __int_as_float(y);
}
#define DPP_QUAD_XOR1 0xB1   // quad_perm [1,0,3,2]
#define DPP_QUAD_XOR2 0x4E   // quad_perm [2,3,0,1]

__device__ __forceinline__ __half2 u2h(uint u) { return __builtin_bit_cast(__half2, u); }
__device__ __forceinline__ uint h2u(__half2 h) { return __builtin_bit_cast(uint, h); }

// ROCm 7.2 hip_fp16.h lacks __hmax2 — emit v_pk_max_f16 directly
__device__ __forceinline__ __half2 hmax2(__half2 a, __half2 b) {
    uint r, ua = h2u(a), ub = h2u(b);
    asm("v_pk_max_f16 %0, %1, %2" : "=v"(r) : "v"(ua), "v"(ub));
    return u2h(r);
}

// ---------------- hist chunks + Wt conversion + attn->f16 (one launch) ----------------
__global__ __launch_bounds__(256) void hist_wt_k(
    const int* __restrict__ dst, int* __restrict__ chunk_hist,
    const float* __restrict__ Wsrc, const float* __restrict__ Wdst,
    ushort* __restrict__ Wt,
    const float* __restrict__ attn, __half* __restrict__ attn_h)
{
    __shared__ int hist[NBKT];
    const int b = blockIdx.x;
    const int tid = threadIdx.x;
    if (b < NCHUNK) {
        const int e0 = b * CHUNK;
        for (int t = tid; t < NBKT; t += 256) hist[t] = 0;
        __syncthreads();
        #pragma unroll
        for (int k = 0; k < 16; ++k) {
            const int e = e0 + k * 256 + tid;
            if (e < NE) atomicAdd(&hist[dst[e] >> 9], 1);
        }
        __syncthreads();
        for (int t = tid; t < NBKT; t += 256)
            chunk_hist[b * NBKT + t] = hist[t];
    } else {
        if (b == NCHUNK && tid < FOUT) attn_h[tid] = __float2half(attn[tid]);
        int t = (b - NCHUNK) * 256 + tid;
        if (t >= 256 * FIN) return;
        int n = t >> 7, k = t & 127;
        float v = (n < 128) ? Wsrc[k * 128 + n] : Wdst[k * 128 + (n - 128)];
        Wt[t] = f2bf(v);
    }
}

// ---------------- scatter (standalone): parallel scan + LDS-cursor bucketing ----------------
__global__ __launch_bounds__(256) void scatter_k(
    const int* __restrict__ dst, const int* __restrict__ src,
    const int* __restrict__ chunk_hist, int* __restrict__ bkbase,
    uint* __restrict__ ebuf)
{
    __shared__ int cur[NBKT];
    __shared__ int tot_s[NBKT];
    __shared__ int par_s[NBKT];
    __shared__ int ps[256];
    const int chunk = blockIdx.x;
    const int tid = threadIdx.x;

    for (int t = tid; t < NBKT; t += 256) { tot_s[t] = 0; par_s[t] = 0; }
    __syncthreads();
    #pragma unroll 4
    for (int i = tid; i < NCHUNK * NBKT; i += 256) {
        const int v = chunk_hist[i];
        const int c = i / NBKT;
        const int t = i - c * NBKT;
        atomicAdd(&tot_s[t], v);
        if (c < chunk) atomicAdd(&par_s[t], v);
    }
    __syncthreads();
    const int total = (tid < NBKT) ? tot_s[tid] : 0;
    ps[tid] = total;
    __syncthreads();
    for (int off = 1; off < 256; off <<= 1) {
        int add = (tid >= off) ? ps[tid - off] : 0;
        __syncthreads();
        ps[tid] += add;
        __syncthreads();
    }
    if (tid < NBKT) cur[tid] = (ps[tid] - total) + par_s[tid];   // bkbase[t] + partial
    if (chunk == 0) {                                            // publish bkbase for binB
        if (tid < NBKT) bkbase[tid] = ps[tid] - total;
        if (tid == 0) bkbase[NBKT] = NE;
    }
    __syncthreads();
    const int e0 = chunk * CHUNK;
    #pragma unroll
    for (int k = 0; k < 16; ++k) {
        const int e = e0 + k * 256 + tid;
        if (e < NE) {
            const int d = dst[e];
            const int p = atomicAdd(&cur[d >> 9], 1);   // LDS atomic
            ebuf[p] = ((uint)d << 16) | (uint)src[e];
        }
    }
}

// ---------------- gemm (standalone): BM=64, x staged ONCE, 4 col-tiles, SWAPPED-operand epilogue ----
// mfma(bb, a) transposes the fragment: each lane holds 4 CONSECUTIVE COLUMNS of one row
// -> one 8B uint2 store per (m,n) instead of four 2B scalar stores (4x fewer store instrs).
__global__ __launch_bounds__(256) void gemm_k(
    const float* __restrict__ x, const ushort* __restrict__ Wt,
    const float* __restrict__ bsrc, const float* __restrict__ bdst,
    __half* __restrict__ fsfd)
{
    __shared__ ushort As[64 * 128];    // 16 KB
    __shared__ ushort Bs[64 * 128];    // 16 KB
    const int tid = threadIdx.x;
    const int bm = blockIdx.x * 64;

    // A tile: read f32 x ONCE, convert to bf16 in-register, swizzled LDS write
    for (int q = tid; q < 64 * 16; q += 256) {
        int r = q >> 4, c16 = q & 15;
        int row = bm + r;
        uint4 o = make_uint4(0u, 0u, 0u, 0u);
        if (row < NN) {
            const float4 a = *(const float4*)&x[(size_t)row * FIN + c16 * 8];
            const float4 c = *(const float4*)&x[(size_t)row * FIN + c16 * 8 + 4];
            o.x = f2bf_u(a.x) | (f2bf_u(a.y) << 16);
            o.y = f2bf_u(a.z) | (f2bf_u(a.w) << 16);
            o.z = f2bf_u(c.x) | (f2bf_u(c.y) << 16);
            o.w = f2bf_u(c.z) | (f2bf_u(c.w) << 16);
        }
        int off = r * 256 + ((c16 * 16) ^ ((r & 7) << 4));
        *(uint4*)((char*)As + off) = o;
    }

    const int wid = tid >> 6, lane = tid & 63;
    const int wr = (wid >> 1) * 32, wc = (wid & 1) * 32;   // 2x2 waves, each 32x32 per ct
    const int lrow = lane & 15;
    const int lk = (lane >> 4) * 16;

    #pragma unroll
    for (int ct = 0; ct < 4; ++ct) {
        if (ct > 0) __syncthreads();
        for (int q = tid; q < 64 * 16; q += 256) {
            int r = q >> 4, c16 = q & 15;
            uint4 v = *(const uint4*)&Wt[(ct * 64 + r) * FIN + c16 * 8];
            int off = r * 256 + ((c16 * 16) ^ ((r & 7) << 4));
            *(uint4*)((char*)Bs + off) = v;
        }
        __syncthreads();

        f32x4 acc[2][2] = {};
        #pragma unroll
        for (int kk = 0; kk < 4; ++kk) {
            bf16x8 a[2], bb[2];
            #pragma unroll
            for (int m = 0; m < 2; ++m) {
                int r = wr + m * 16 + lrow;
                int off = r * 256 + ((kk * 64 + lk) ^ ((r & 7) << 4));
                a[m] = *(bf16x8*)((char*)As + off);
            }
            #pragma unroll
            for (int n = 0; n < 2; ++n) {
                int r = wc + n * 16 + lrow;
                int off = r * 256 + ((kk * 64 + lk) ^ ((r & 7) << 4));
                bb[n] = *(bf16x8*)((char*)Bs + off);
            }
            // SWAPPED operands: output transposed vs previous rounds
            #pragma unroll
            for (int m = 0; m < 2; ++m)
                #pragma unroll
                for (int n = 0; n < 2; ++n)
                    acc[m][n] = __builtin_amdgcn_mfma_f32_16x16x32_bf16(bb[n], a[m], acc[m][n], 0, 0, 0);
        }

        // epilogue: lane holds row grow = ...+(lane&15), cols gcolb..gcolb+3 -> one 8B store
        #pragma unroll
        for (int m = 0; m < 2; ++m) {
            const int grow = bm + wr + m * 16 + (lane & 15);
            if (grow >= NN) continue;
            #pragma unroll
            for (int n = 0; n < 2; ++n) {
                const int gcolb = ct * 64 + wc + n * 16 + (lane >> 4) * 4;
                const float4 b4 = (gcolb < 128) ? *(const float4*)&bsrc[gcolb]
                                                : *(const float4*)&bdst[gcolb - 128];
                uint lo = f2h_u(acc[m][n][0] + b4.x) | (f2h_u(acc[m][n][1] + b4.y) << 16);
                uint hi = f2h_u(acc[m][n][2] + b4.z) | (f2h_u(acc[m][n][3] + b4.w) << 16);
                *(uint2*)&fsfd[(size_t)grow * 256 + gcolb] = make_uint2(lo, hi);
            }
        }
    }
}

// ---------------- binB: per-bucket rowptr build (LDS) + coalesced nbr ----------------
__global__ __launch_bounds__(256) void binB_k(
    const uint* __restrict__ ebuf, const int* __restrict__ bkbase,
    int* __restrict__ rowptr, ushort* __restrict__ nbr)
{
    __shared__ int cnt_s[512];
    __shared__ int ps[256];
    __shared__ ushort buf[BCAP];
    const int b = blockIdx.x;
    const int tid = threadIdx.x;
    const int node0 = b << 9;
    const int nodes = (node0 + 512 < NN) ? 512 : (NN - node0);
    const int segbase = bkbase[b];
    const int segend  = bkbase[b + 1];
    const int seglen  = segend - segbase;

    cnt_s[tid] = 0;
    cnt_s[tid + 256] = 0;
    __syncthreads();
    for (int i = segbase + tid; i < segend; i += 256)
        atomicAdd(&cnt_s[(int)(ebuf[i] >> 16) - node0], 1);   // LDS atomic
    __syncthreads();

    const int c0 = cnt_s[2 * tid], c1 = cnt_s[2 * tid + 1];
    const int pair = c0 + c1;
    ps[tid] = pair;
    __syncthreads();
    for (int off = 1; off < 256; off <<= 1) {
        int add = (tid >= off) ? ps[tid - off] : 0;
        __syncthreads();
        ps[tid] += add;
        __syncthreads();
    }
    const int ex = ps[tid] - pair;
    __syncthreads();
    cnt_s[2 * tid] = ex;
    cnt_s[2 * tid + 1] = ex + c0;
    if (2 * tid < nodes)     rowptr[node0 + 2 * tid]     = segbase + ex;
    if (2 * tid + 1 < nodes) rowptr[node0 + 2 * tid + 1] = segbase + ex + c0;
    if (b == NBKT - 1 && tid == 0) rowptr[NN] = segend;
    __syncthreads();

    if (seglen <= BCAP) {
        for (int i = segbase + tid; i < segend; i += 256) {
            const uint e = ebuf[i];
            const int d = (int)(e >> 16) - node0;
            const int p = atomicAdd(&cnt_s[d], 1);
            buf[p] = (ushort)(e & 0xffffu);
        }
        __syncthreads();
        for (int i = tid; i < seglen; i += 256)
            nbr[segbase + i] = buf[i];
    } else {
        for (int i = segbase + tid; i < segend; i += 256) {
            const uint e = ebuf[i];
            const int d = (int)(e >> 16) - node0;
            const int p = atomicAdd(&cnt_s[d], 1);
            nbr[segbase + p] = (ushort)(e & 0xffffu);
        }
    }
}

// ---------------- Fused per-node GAT kernel (packed f16, 4 gathers in flight) ----------------
__global__ __launch_bounds__(256) void gat_node_k(
    const __half* __restrict__ fsfd, const __half* __restrict__ attn_h,
    const int* __restrict__ rowptr, const ushort* __restrict__ nbr,
    float* __restrict__ out)
{
    const int node = blockIdx.x * 4 + (threadIdx.x >> 6);
    const int lane = threadIdx.x & 63;
    const int ql = lane & 15;
    const int q  = lane >> 4;

    const uint4 ufd = *(const uint4*)&fsfd[(size_t)node * 256 + 128 + 8 * ql];
    const __half2 fd0 = u2h(ufd.x), fd1 = u2h(ufd.y), fd2 = u2h(ufd.z), fd3 = u2h(ufd.w);
    const uint4 uav = *(const uint4*)&attn_h[8 * ql];
    const __half2 av0 = u2h(uav.x), av1 = u2h(uav.y), av2 = u2h(uav.z), av3 = u2h(uav.w);
    const __half2 k02 = __float2half2_rn(NEG);

    const int beg = rowptr[node];
    const int end = rowptr[node + 1];

    float den = 0.f;
    __half2 acc0 = u2h(0), acc1 = u2h(0), acc2 = u2h(0), acc3 = u2h(0);

    for (int i = beg; i < end; i += 16) {
        #pragma unroll
        for (int j = 0; j < 4; ++j) {
            const int idx = i + 4 * j + q;
            const bool valid = idx < end;
            const int s = nbr[valid ? idx : end - 1];
            const uint4 u = *(const uint4*)&fsfd[(size_t)s * 256 + 8 * ql];
            const __half2 f0 = u2h(u.x), f1 = u2h(u.y), f2 = u2h(u.z), f3 = u2h(u.w);
            __half2 v0 = __hadd2(f0, fd0), v1 = __hadd2(f1, fd1);
            __half2 v2 = __hadd2(f2, fd2), v3 = __hadd2(f3, fd3);
            v0 = hmax2(v0, __hmul2(v0, k02));
            v1 = hmax2(v1, __hmul2(v1, k02));
            v2 = hmax2(v2, __hmul2(v2, k02));
            v3 = hmax2(v3, __hmul2(v3, k02));
            __half2 sch = __hmul2(v0, av0);
            sch = __hfma2(v1, av1, sch);
            sch = __hfma2(v2, av2, sch);
            sch = __hfma2(v3, av3, sch);
            float sc = __low2float(sch) + __high2float(sch);
            sc = dpp_add<DPP_QUAD_XOR1>(sc);
            sc = dpp_add<DPP_QUAD_XOR2>(sc);
            float ex = __expf(sc);
            ex = valid ? ex : 0.f;
            den += ex;
            const __half2 exh = __float2half2_rn(ex);
            acc0 = __hfma2(exh, f0, acc0);
            acc1 = __hfma2(exh, f1, acc1);
            acc2 = __hfma2(exh, f2, acc2);
            acc3 = __hfma2(exh, f3, acc3);
        }
    }

    den += __shfl_xor(den, 16, 64);
    den += __shfl_xor(den, 32, 64);
    uint ua0 = h2u(acc0), ua1 = h2u(acc1), ua2 = h2u(acc2), ua3 = h2u(acc3);
    ua0 = h2u(__hadd2(u2h(ua0), u2h((uint)__shfl_xor((int)ua0, 16, 64))));
    ua1 = h2u(__hadd2(u2h(ua1), u2h((uint)__shfl_xor((int)ua1, 16, 64))));
    ua2 = h2u(__hadd2(u2h(ua2), u2h((uint)__shfl_xor((int)ua2, 16, 64))));
    ua3 = h2u(__hadd2(u2h(ua3), u2h((uint)__shfl_xor((int)ua3, 16, 64))));
    ua0 = h2u(__hadd2(u2h(ua0), u2h((uint)__shfl_xor((int)ua0, 32, 64))));
    ua1 = h2u(__hadd2(u2h(ua1), u2h((uint)__shfl_xor((int)ua1, 32, 64))));
    ua2 = h2u(__hadd2(u2h(ua2), u2h((uint)__shfl_xor((int)ua2, 32, 64))));
    ua3 = h2u(__hadd2(u2h(ua3), u2h((uint)__shfl_xor((int)ua3, 32, 64))));

    if (q == 0) {
        const float inv = (den > 0.f) ? 1.f / den : 0.f;
        float4 o0, o1;
        o0.x = fmaxf(__low2float(u2h(ua0))  * inv, 0.f);
        o0.y = fmaxf(__high2float(u2h(ua0)) * inv, 0.f);
        o0.z = fmaxf(__low2float(u2h(ua1))  * inv, 0.f);
        o0.w = fmaxf(__high2float(u2h(ua1)) * inv, 0.f);
        o1.x = fmaxf(__low2float(u2h(ua2))  * inv, 0.f);
        o1.y = fmaxf(__high2float(u2h(ua2)) * inv, 0.f);
        o1.z = fmaxf(__low2float(u2h(ua3))  * inv, 0.f);
        o1.w = fmaxf(__high2float(u2h(ua3)) * inv, 0.f);
        *(float4*)&out[(size_t)node * FOUT + 8 * ql] = o0;
        *(float4*)&out[(size_t)node * FOUT + 8 * ql + 4] = o1;
    }
}

extern "C" void kernel_launch(void* const* d_in, const int* in_sizes, int n_in,
                              void* d_out, int out_size, void* d_ws, size_t ws_size,
                              hipStream_t stream)
{
    const float* x    = (const float*)d_in[0];
    const int*   src  = (const int*)d_in[1];
    const int*   dst  = (const int*)d_in[2];
    const float* Wsrc = (const float*)d_in[3];
    const float* bsrc = (const float*)d_in[4];
    const float* Wdst = (const float*)d_in[5];
    const float* bdst = (const float*)d_in[6];
    const float* attn = (const float*)d_in[7];
    float* out = (float*)d_out;

    ushort* Wt      = (ushort*)d_ws;                      // 256*128 bf16
    __half* fsfd    = (__half*)(Wt + 256 * FIN);          // NN*256 f16
    int* chunk_hist = (int*)(fsfd + (size_t)NN * 256);    // NCHUNK*NBKT
    int* bkbase     = chunk_hist + NCHUNK * NBKT;         // NBKT+1
    int* rowptr     = bkbase + NBKT + 1;                  // NN+1
    uint* ebuf      = (uint*)(rowptr + NN + 1);           // NE packed (d<<16)|s
    ushort* nbr     = (ushort*)(ebuf + NE);               // NE u16
    __half* attn_h  = (__half*)(nbr + NE);                // 128 f16

    hist_wt_k<<<NCHUNK + NB_W, 256, 0, stream>>>(dst, chunk_hist, Wsrc, Wdst, Wt, attn, attn_h);
    scatter_k<<<NCHUNK, 256, 0, stream>>>(dst, src, chunk_hist, bkbase, ebuf);
    binB_k<<<NBKT, 256, 0, stream>>>(ebuf, bkbase, rowptr, nbr);
    gemm_k<<<N_GEMM, 256, 0, stream>>>(x, Wt, bsrc, bdst, fsfd);
    gat_node_k<<<(NN + 3) / 4, 256, 0, stream>>>(fsfd, attn_h, rowptr, nbr, out);
}

// Round 19
// 92.450 us; speedup vs baseline: 1.1625x; 1.1625x over previous
//
#include <hip/hip_runtime.h>
#include <hip/hip_fp16.h>

#define NN 50000
#define NE 800000
#define FIN 128
#define NH 4
#define HD 32
#define FOUT 128   // NH*HD
#define NEG 0.2f
#define NB_W    ((256 * FIN + 255) / 256) // 128
#define N_GEMM  782                  // 64-row stripes; each block does all 4 col-tiles
#define NBKT    98                   // dst>>9 buckets (512 nodes each)
#define CHUNK   4096                 // edges per hist/scatter chunk
#define NCHUNK  ((NE + CHUNK - 1) / CHUNK)  // 196
#define GB_GRID 980                  // b%5==0 -> scatter (196), else gemm (782 used)
#define BCAP    12288                // binB LDS segment capacity (mean 8163, max ~8600)

typedef __attribute__((ext_vector_type(8))) short bf16x8;
typedef __attribute__((ext_vector_type(4))) float f32x4;

__device__ __forceinline__ uint f2bf_u(float f) {
    uint u = __float_as_uint(f);
    u += 0x7FFF + ((u >> 16) & 1);   // round-to-nearest-even
    return u >> 16;
}
__device__ __forceinline__ ushort f2bf(float f) { return (ushort)f2bf_u(f); }
__device__ __forceinline__ uint f2h_u(float f) {
    return (uint)__builtin_bit_cast(ushort, __float2half(f));
}

template<int CTRL>
__device__ __forceinline__ float dpp_add(float x) {
    int y = __builtin_amdgcn_update_dpp(0, __float_as_int(x), CTRL, 0xF, 0xF, false);
    return x + __int_as_float(y);
}
#define DPP_QUAD_XOR1 0xB1   // quad_perm [1,0,3,2]
#define DPP_QUAD_XOR2 0x4E   // quad_perm [2,3,0,1]

__device__ __forceinline__ __half2 u2h(uint u) { return __builtin_bit_cast(__half2, u); }
__device__ __forceinline__ uint h2u(__half2 h) { return __builtin_bit_cast(uint, h); }

// ROCm 7.2 hip_fp16.h lacks __hmax2 — emit v_pk_max_f16 directly
__device__ __forceinline__ __half2 hmax2(__half2 a, __half2 b) {
    uint r, ua = h2u(a), ub = h2u(b);
    asm("v_pk_max_f16 %0, %1, %2" : "=v"(r) : "v"(ua), "v"(ub));
    return u2h(r);
}

// ---------------- hist chunks + Wt conversion + attn->f16 (one launch) ----------------
__global__ __launch_bounds__(256) void hist_wt_k(
    const int* __restrict__ dst, int* __restrict__ chunk_hist,
    const float* __restrict__ Wsrc, const float* __restrict__ Wdst,
    ushort* __restrict__ Wt,
    const float* __restrict__ attn, __half* __restrict__ attn_h)
{
    __shared__ int hist[NBKT];
    const int b = blockIdx.x;
    const int tid = threadIdx.x;
    if (b < NCHUNK) {
        const int e0 = b * CHUNK;
        for (int t = tid; t < NBKT; t += 256) hist[t] = 0;
        __syncthreads();
        #pragma unroll
        for (int k = 0; k < 16; ++k) {
            const int e = e0 + k * 256 + tid;
            if (e < NE) atomicAdd(&hist[dst[e] >> 9], 1);
        }
        __syncthreads();
        for (int t = tid; t < NBKT; t += 256)
            chunk_hist[b * NBKT + t] = hist[t];
    } else {
        if (b == NCHUNK && tid < FOUT) attn_h[tid] = __float2half(attn[tid]);
        int t = (b - NCHUNK) * 256 + tid;
        if (t >= 256 * FIN) return;
        int n = t >> 7, k = t & 127;
        float v = (n < 128) ? Wsrc[k * 128 + n] : Wdst[k * 128 + (n - 128)];
        Wt[t] = f2bf(v);
    }
}

// ---------------- FUSED: MFMA GEMM (single-barrier, B from global regs) + scatter ----------------
// b % 5 == 0 -> scatter chunk b/5 (196, serial per-thread scan — round-16 best variant);
// else gemm stripe g = b - b/5 - 1 (782 used).
// gemm: A staged once in LDS (ONE barrier); B fragments loaded straight from L2-resident Wt
// into registers -> zero per-col-tile barriers (removes the 8x barrier-drain serialization).
__global__ __launch_bounds__(256) void gemm_scatter_k(
    const float* __restrict__ x, const ushort* __restrict__ Wt,
    const float* __restrict__ bsrc, const float* __restrict__ bdst,
    __half* __restrict__ fsfd,
    const int* __restrict__ dst, const int* __restrict__ src,
    const int* __restrict__ chunk_hist, int* __restrict__ bkbase,
    uint* __restrict__ ebuf)
{
    __shared__ ushort As[64 * 128];    // 16 KB
    __shared__ int cur[NBKT];
    __shared__ int ps[256];
    const int b = blockIdx.x;
    const int tid = threadIdx.x;

    if (b % 5 == 0) {
        // ---- scatter role: per-thread column scan (round-16 variant, measured best) ----
        const int chunk = b / 5;
        int total = 0, part = 0;
        if (tid < NBKT) {
            for (int c = 0; c < NCHUNK; ++c) {
                const int h = chunk_hist[c * NBKT + tid];
                total += h;
                part += (c < chunk) ? h : 0;
            }
        }
        ps[tid] = (tid < NBKT) ? total : 0;
        __syncthreads();
        for (int off = 1; off < 256; off <<= 1) {
            int add = (tid >= off) ? ps[tid - off] : 0;
            __syncthreads();
            ps[tid] += add;
            __syncthreads();
        }
        if (tid < NBKT) cur[tid] = (ps[tid] - total) + part;   // bkbase[t] + partial
        if (chunk == 0) {                                      // publish bkbase for binB
            if (tid < NBKT) bkbase[tid] = ps[tid] - total;
            if (tid == 0) bkbase[NBKT] = NE;
        }
        __syncthreads();
        const int e0 = chunk * CHUNK;
        #pragma unroll
        for (int k = 0; k < 16; ++k) {
            const int e = e0 + k * 256 + tid;
            if (e < NE) {
                const int d = dst[e];
                const int p = atomicAdd(&cur[d >> 9], 1);   // LDS atomic
                ebuf[p] = ((uint)d << 16) | (uint)src[e];
            }
        }
        return;
    }

    // ---- gemm role: one 64-row stripe; x staged ONCE; B from global; ONE barrier total ----
    const int g = b - b / 5 - 1;
    if (g >= N_GEMM) return;
    const int bm = g * 64;

    // A tile: read f32 x ONCE, convert to bf16 in-register, swizzled LDS write
    for (int q = tid; q < 64 * 16; q += 256) {
        int r = q >> 4, c16 = q & 15;
        int row = bm + r;
        uint4 o = make_uint4(0u, 0u, 0u, 0u);
        if (row < NN) {
            const float4 a = *(const float4*)&x[(size_t)row * FIN + c16 * 8];
            const float4 c = *(const float4*)&x[(size_t)row * FIN + c16 * 8 + 4];
            o.x = f2bf_u(a.x) | (f2bf_u(a.y) << 16);
            o.y = f2bf_u(a.z) | (f2bf_u(a.w) << 16);
            o.z = f2bf_u(c.x) | (f2bf_u(c.y) << 16);
            o.w = f2bf_u(c.z) | (f2bf_u(c.w) << 16);
        }
        int off = r * 256 + ((c16 * 16) ^ ((r & 7) << 4));
        *(uint4*)((char*)As + off) = o;
    }
    __syncthreads();   // the ONLY barrier in the gemm role

    const int wid = tid >> 6, lane = tid & 63;
    const int wr = (wid >> 1) * 32, wc = (wid & 1) * 32;   // 2x2 waves, each 32x32 per ct
    const int lrow = lane & 15;
    const int lk = (lane >> 4) * 16;   // byte offset of this lane's k-subchunk
    const int kel = (lane >> 4) * 8;   // element offset (bf16) of this lane's k-subchunk

    #pragma unroll
    for (int ct = 0; ct < 4; ++ct) {
        f32x4 acc[2][2] = {};
        #pragma unroll
        for (int kk = 0; kk < 4; ++kk) {
            bf16x8 a[2], bb[2];
            #pragma unroll
            for (int m = 0; m < 2; ++m) {
                int r = wr + m * 16 + lrow;
                int off = r * 256 + ((kk * 64 + lk) ^ ((r & 7) << 4));
                a[m] = *(bf16x8*)((char*)As + off);
            }
            #pragma unroll
            for (int n = 0; n < 2; ++n) {
                // direct from global (L2-resident Wt): row = output col, 16B per lane
                bb[n] = *(const bf16x8*)&Wt[(ct * 64 + wc + n * 16 + lrow) * FIN + kk * 32 + kel];
            }
            // SWAPPED operands: lane holds 4 consecutive cols of one row
            #pragma unroll
            for (int m = 0; m < 2; ++m)
                #pragma unroll
                for (int n = 0; n < 2; ++n)
                    acc[m][n] = __builtin_amdgcn_mfma_f32_16x16x32_bf16(bb[n], a[m], acc[m][n], 0, 0, 0);
        }

        // epilogue: one 8B uint2 store per (m,n)
        #pragma unroll
        for (int m = 0; m < 2; ++m) {
            const int grow = bm + wr + m * 16 + (lane & 15);
            if (grow >= NN) continue;
            #pragma unroll
            for (int n = 0; n < 2; ++n) {
                const int gcolb = ct * 64 + wc + n * 16 + (lane >> 4) * 4;
                const float4 b4 = (gcolb < 128) ? *(const float4*)&bsrc[gcolb]
                                                : *(const float4*)&bdst[gcolb - 128];
                uint lo = f2h_u(acc[m][n][0] + b4.x) | (f2h_u(acc[m][n][1] + b4.y) << 16);
                uint hi = f2h_u(acc[m][n][2] + b4.z) | (f2h_u(acc[m][n][3] + b4.w) << 16);
                *(uint2*)&fsfd[(size_t)grow * 256 + gcolb] = make_uint2(lo, hi);
            }
        }
    }
}

// ---------------- binB: per-bucket rowptr build (LDS) + coalesced nbr ----------------
__global__ __launch_bounds__(256) void binB_k(
    const uint* __restrict__ ebuf, const int* __restrict__ bkbase,
    int* __restrict__ rowptr, ushort* __restrict__ nbr)
{
    __shared__ int cnt_s[512];
    __shared__ int ps[256];
    __shared__ ushort buf[BCAP];
    const int b = blockIdx.x;
    const int tid = threadIdx.x;
    const int node0 = b << 9;
    const int nodes = (node0 + 512 < NN) ? 512 : (NN - node0);
    const int segbase = bkbase[b];
    const int segend  = bkbase[b + 1];
    const int seglen  = segend - segbase;

    cnt_s[tid] = 0;
    cnt_s[tid + 256] = 0;
    __syncthreads();
    for (int i = segbase + tid; i < segend; i += 256)
        atomicAdd(&cnt_s[(int)(ebuf[i] >> 16) - node0], 1);   // LDS atomic
    __syncthreads();

    const int c0 = cnt_s[2 * tid], c1 = cnt_s[2 * tid + 1];
    const int pair = c0 + c1;
    ps[tid] = pair;
    __syncthreads();
    for (int off = 1; off < 256; off <<= 1) {
        int add = (tid >= off) ? ps[tid - off] : 0;
        __syncthreads();
        ps[tid] += add;
        __syncthreads();
    }
    const int ex = ps[tid] - pair;
    __syncthreads();
    cnt_s[2 * tid] = ex;
    cnt_s[2 * tid + 1] = ex + c0;
    if (2 * tid < nodes)     rowptr[node0 + 2 * tid]     = segbase + ex;
    if (2 * tid + 1 < nodes) rowptr[node0 + 2 * tid + 1] = segbase + ex + c0;
    if (b == NBKT - 1 && tid == 0) rowptr[NN] = segend;
    __syncthreads();

    if (seglen <= BCAP) {
        for (int i = segbase + tid; i < segend; i += 256) {
            const uint e = ebuf[i];
            const int d = (int)(e >> 16) - node0;
            const int p = atomicAdd(&cnt_s[d], 1);
            buf[p] = (ushort)(e & 0xffffu);
        }
        __syncthreads();
        for (int i = tid; i < seglen; i += 256)
            nbr[segbase + i] = buf[i];
    } else {
        for (int i = segbase + tid; i < segend; i += 256) {
            const uint e = ebuf[i];
            const int d = (int)(e >> 16) - node0;
            const int p = atomicAdd(&cnt_s[d], 1);
            nbr[segbase + p] = (ushort)(e & 0xffffu);
        }
    }
}

// ---------------- Fused per-node GAT kernel (packed f16, 4 gathers in flight) ----------------
__global__ __launch_bounds__(256) void gat_node_k(
    const __half* __restrict__ fsfd, const __half* __restrict__ attn_h,
    const int* __restrict__ rowptr, const ushort* __restrict__ nbr,
    float* __restrict__ out)
{
    const int node = blockIdx.x * 4 + (threadIdx.x >> 6);
    const int lane = threadIdx.x & 63;
    const int ql = lane & 15;
    const int q  = lane >> 4;

    const uint4 ufd = *(const uint4*)&fsfd[(size_t)node * 256 + 128 + 8 * ql];
    const __half2 fd0 = u2h(ufd.x), fd1 = u2h(ufd.y), fd2 = u2h(ufd.z), fd3 = u2h(ufd.w);
    const uint4 uav = *(const uint4*)&attn_h[8 * ql];
    const __half2 av0 = u2h(uav.x), av1 = u2h(uav.y), av2 = u2h(uav.z), av3 = u2h(uav.w);
    const __half2 k02 = __float2half2_rn(NEG);

    const int beg = rowptr[node];
    const int end = rowptr[node + 1];

    float den = 0.f;
    __half2 acc0 = u2h(0), acc1 = u2h(0), acc2 = u2h(0), acc3 = u2h(0);

    for (int i = beg; i < end; i += 16) {
        #pragma unroll
        for (int j = 0; j < 4; ++j) {
            const int idx = i + 4 * j + q;
            const bool valid = idx < end;
            const int s = nbr[valid ? idx : end - 1];
            const uint4 u = *(const uint4*)&fsfd[(size_t)s * 256 + 8 * ql];
            const __half2 f0 = u2h(u.x), f1 = u2h(u.y), f2 = u2h(u.z), f3 = u2h(u.w);
            __half2 v0 = __hadd2(f0, fd0), v1 = __hadd2(f1, fd1);
            __half2 v2 = __hadd2(f2, fd2), v3 = __hadd2(f3, fd3);
            v0 = hmax2(v0, __hmul2(v0, k02));
            v1 = hmax2(v1, __hmul2(v1, k02));
            v2 = hmax2(v2, __hmul2(v2, k02));
            v3 = hmax2(v3, __hmul2(v3, k02));
            __half2 sch = __hmul2(v0, av0);
            sch = __hfma2(v1, av1, sch);
            sch = __hfma2(v2, av2, sch);
            sch = __hfma2(v3, av3, sch);
            float sc = __low2float(sch) + __high2float(sch);
            sc = dpp_add<DPP_QUAD_XOR1>(sc);
            sc = dpp_add<DPP_QUAD_XOR2>(sc);
            float ex = __expf(sc);
            ex = valid ? ex : 0.f;
            den += ex;
            const __half2 exh = __float2half2_rn(ex);
            acc0 = __hfma2(exh, f0, acc0);
            acc1 = __hfma2(exh, f1, acc1);
            acc2 = __hfma2(exh, f2, acc2);
            acc3 = __hfma2(exh, f3, acc3);
        }
    }

    den += __shfl_xor(den, 16, 64);
    den += __shfl_xor(den, 32, 64);
    uint ua0 = h2u(acc0), ua1 = h2u(acc1), ua2 = h2u(acc2), ua3 = h2u(acc3);
    ua0 = h2u(__hadd2(u2h(ua0), u2h((uint)__shfl_xor((int)ua0, 16, 64))));
    ua1 = h2u(__hadd2(u2h(ua1), u2h((uint)__shfl_xor((int)ua1, 16, 64))));
    ua2 = h2u(__hadd2(u2h(ua2), u2h((uint)__shfl_xor((int)ua2, 16, 64))));
    ua3 = h2u(__hadd2(u2h(ua3), u2h((uint)__shfl_xor((int)ua3, 16, 64))));
    ua0 = h2u(__hadd2(u2h(ua0), u2h((uint)__shfl_xor((int)ua0, 32, 64))));
    ua1 = h2u(__hadd2(u2h(ua1), u2h((uint)__shfl_xor((int)ua1, 32, 64))));
    ua2 = h2u(__hadd2(u2h(ua2), u2h((uint)__shfl_xor((int)ua2, 32, 64))));
    ua3 = h2u(__hadd2(u2h(ua3), u2h((uint)__shfl_xor((int)ua3, 32, 64))));

    if (q == 0) {
        const float inv = (den > 0.f) ? 1.f / den : 0.f;
        float4 o0, o1;
        o0.x = fmaxf(__low2float(u2h(ua0))  * inv, 0.f);
        o0.y = fmaxf(__high2float(u2h(ua0)) * inv, 0.f);
        o0.z = fmaxf(__low2float(u2h(ua1))  * inv, 0.f);
        o0.w = fmaxf(__high2float(u2h(ua1)) * inv, 0.f);
        o1.x = fmaxf(__low2float(u2h(ua2))  * inv, 0.f);
        o1.y = fmaxf(__high2float(u2h(ua2)) * inv, 0.f);
        o1.z = fmaxf(__low2float(u2h(ua3))  * inv, 0.f);
        o1.w = fmaxf(__high2float(u2h(ua3)) * inv, 0.f);
        *(float4*)&out[(size_t)node * FOUT + 8 * ql] = o0;
        *(float4*)&out[(size_t)node * FOUT + 8 * ql + 4] = o1;
    }
}

extern "C" void kernel_launch(void* const* d_in, const int* in_sizes, int n_in,
                              void* d_out, int out_size, void* d_ws, size_t ws_size,
                              hipStream_t stream)
{
    const float* x    = (const float*)d_in[0];
    const int*   src  = (const int*)d_in[1];
    const int*   dst  = (const int*)d_in[2];
    const float* Wsrc = (const float*)d_in[3];
    const float* bsrc = (const float*)d_in[4];
    const float* Wdst = (const float*)d_in[5];
    const float* bdst = (const float*)d_in[6];
    const float* attn = (const float*)d_in[7];
    float* out = (float*)d_out;

    ushort* Wt      = (ushort*)d_ws;                      // 256*128 bf16
    __half* fsfd    = (__half*)(Wt + 256 * FIN);          // NN*256 f16
    int* chunk_hist = (int*)(fsfd + (size_t)NN * 256);    // NCHUNK*NBKT
    int* bkbase     = chunk_hist + NCHUNK * NBKT;         // NBKT+1
    int* rowptr     = bkbase + NBKT + 1;                  // NN+1
    uint* ebuf      = (uint*)(rowptr + NN + 1);           // NE packed (d<<16)|s
    ushort* nbr     = (ushort*)(ebuf + NE);               // NE u16
    __half* attn_h  = (__half*)(nbr + NE);                // 128 f16

    hist_wt_k<<<NCHUNK + NB_W, 256, 0, stream>>>(dst, chunk_hist, Wsrc, Wdst, Wt, attn, attn_h);
    gemm_scatter_k<<<GB_GRID, 256, 0, stream>>>(x, Wt, bsrc, bdst, fsfd,
                                                dst, src, chunk_hist, bkbase, ebuf);
    binB_k<<<NBKT, 256, 0, stream>>>(ebuf, bkbase, rowptr, nbr);
    gat_node_k<<<(NN + 3) / 4, 256, 0, stream>>>(fsfd, attn_h, rowptr, nbr, out);
}

// Round 20
// 86.926 us; speedup vs baseline: 1.2364x; 1.0636x over previous
//
#include <hip/hip_runtime.h>
#include <hip/hip_fp16.h>

#define NN 50000
#define NE 800000
#define FIN 128
#define NH 4
#define HD 32
#define FOUT 128   // NH*HD
#define NEG 0.2f
#define NB_W    ((256 * FIN + 255) / 256) // 128
#define N_GEMM  782                  // 64-row stripes; each block does all 4 col-tiles
#define NBKT    98                   // dst>>9 buckets (512 nodes each)
#define CHUNK   4096                 // edges per hist/scatter chunk
#define NCHUNK  ((NE + CHUNK - 1) / CHUNK)  // 196
#define GB_GRID 980                  // b%5==0 -> scatter (196), else gemm (782 used)
#define BCAP    12288                // binB LDS segment capacity (mean 8163, max ~8600)

typedef __attribute__((ext_vector_type(8))) short bf16x8;
typedef __attribute__((ext_vector_type(4))) float f32x4;

__device__ __forceinline__ uint f2bf_u(float f) {
    uint u = __float_as_uint(f);
    u += 0x7FFF + ((u >> 16) & 1);   // round-to-nearest-even
    return u >> 16;
}
__device__ __forceinline__ ushort f2bf(float f) { return (ushort)f2bf_u(f); }
__device__ __forceinline__ uint f2h_u(float f) {
    return (uint)__builtin_bit_cast(ushort, __float2half(f));
}

template<int CTRL>
__device__ __forceinline__ float dpp_add(float x) {
    int y = __builtin_amdgcn_update_dpp(0, __float_as_int(x), CTRL, 0xF, 0xF, false);
    return x + __int_as_float(y);
}
#define DPP_QUAD_XOR1 0xB1   // quad_perm [1,0,3,2]
#define DPP_QUAD_XOR2 0x4E   // quad_perm [2,3,0,1]

__device__ __forceinline__ __half2 u2h(uint u) { return __builtin_bit_cast(__half2, u); }
__device__ __forceinline__ uint h2u(__half2 h) { return __builtin_bit_cast(uint, h); }

// ROCm 7.2 hip_fp16.h lacks __hmax2 — emit v_pk_max_f16 directly
__device__ __forceinline__ __half2 hmax2(__half2 a, __half2 b) {
    uint r, ua = h2u(a), ub = h2u(b);
    asm("v_pk_max_f16 %0, %1, %2" : "=v"(r) : "v"(ua), "v"(ub));
    return u2h(r);
}

// ---------------- hist chunks + Wt conversion + attn->f16 (one launch) ----------------
__global__ __launch_bounds__(256) void hist_wt_k(
    const int* __restrict__ dst, int* __restrict__ chunk_hist,
    const float* __restrict__ Wsrc, const float* __restrict__ Wdst,
    ushort* __restrict__ Wt,
    const float* __restrict__ attn, __half* __restrict__ attn_h)
{
    __shared__ int hist[NBKT];
    const int b = blockIdx.x;
    const int tid = threadIdx.x;
    if (b < NCHUNK) {
        const int e0 = b * CHUNK;
        for (int t = tid; t < NBKT; t += 256) hist[t] = 0;
        __syncthreads();
        #pragma unroll
        for (int k = 0; k < 16; ++k) {
            const int e = e0 + k * 256 + tid;
            if (e < NE) atomicAdd(&hist[dst[e] >> 9], 1);
        }
        __syncthreads();
        for (int t = tid; t < NBKT; t += 256)
            chunk_hist[b * NBKT + t] = hist[t];
    } else {
        if (b == NCHUNK && tid < FOUT) attn_h[tid] = __float2half(attn[tid]);
        int t = (b - NCHUNK) * 256 + tid;
        if (t >= 256 * FIN) return;
        int n = t >> 7, k = t & 127;
        float v = (n < 128) ? Wsrc[k * 128 + n] : Wdst[k * 128 + (n - 128)];
        Wt[t] = f2bf(v);
    }
}

// ---------------- FUSED: MFMA GEMM (round-16 structure) + LDS-sorted coalesced scatter ----------------
// b % 5 == 0 -> scatter chunk b/5: local counting sort in LDS, then LINEAR write-out
//   (consecutive threads -> consecutive ebuf addresses within bucket runs) — replaces
//   4096 fully-scattered stores/block, the suspected straggler cost of rounds 15-19.
// else gemm stripe g = b - b/5 - 1 (782 used): BM=64, Bs LDS per col-tile, swapped-operand
//   MFMA (lane holds 4 consecutive cols of one row -> single uint2 store per fragment).
__global__ __launch_bounds__(256) void gemm_scatter_k(
    const float* __restrict__ x, const ushort* __restrict__ Wt,
    const float* __restrict__ bsrc, const float* __restrict__ bdst,
    __half* __restrict__ fsfd,
    const int* __restrict__ dst, const int* __restrict__ src,
    const int* __restrict__ chunk_hist, int* __restrict__ bkbase,
    uint* __restrict__ ebuf)
{
    __shared__ ushort As[64 * 128];    // 16 KB (scatter role aliases this as stage[4096])
    __shared__ ushort Bs[64 * 128];    // 16 KB
    __shared__ int ps[256];
    __shared__ int gbase[NBKT];
    __shared__ int lcur[NBKT];
    __shared__ int delta[NBKT];
    const int b = blockIdx.x;
    const int tid = threadIdx.x;

    if (b % 5 == 0) {
        // ---- scatter role ----
        const int chunk = b / 5;
        uint* stage = (uint*)As;                     // 4096 entries

        // (1) global bucket bases: serial per-thread column scan (NOT the bottleneck, m17 ablation)
        int total = 0, part = 0;
        if (tid < NBKT) {
            for (int c = 0; c < NCHUNK; ++c) {
                const int h = chunk_hist[c * NBKT + tid];
                total += h;
                part += (c < chunk) ? h : 0;
            }
        }
        ps[tid] = (tid < NBKT) ? total : 0;
        __syncthreads();
        for (int off = 1; off < 256; off <<= 1) {
            int add = (tid >= off) ? ps[tid - off] : 0;
            __syncthreads();
            ps[tid] += add;
            __syncthreads();
        }
        if (tid < NBKT) gbase[tid] = (ps[tid] - total) + part;   // bkbase[t] + chunk partial
        if (chunk == 0) {
            if (tid < NBKT) bkbase[tid] = ps[tid] - total;
            if (tid == 0) bkbase[NBKT] = NE;
        }
        if (tid < NBKT) lcur[tid] = 0;               // reuse as local hist first
        __syncthreads();

        // (2) load edges + local histogram
        const int e0 = chunk * CHUNK;
        int d[16], s[16];
        #pragma unroll
        for (int k = 0; k < 16; ++k) {
            const int e = e0 + k * 256 + tid;
            if (e < NE) {
                d[k] = dst[e];
                s[k] = src[e];
                atomicAdd(&lcur[d[k] >> 9], 1);
            } else d[k] = -1;
        }
        __syncthreads();

        // (3) local exclusive scan -> loff; delta[t] = gbase[t] - loff[t]; lcur[t] = loff[t]
        const int lv = (tid < NBKT) ? lcur[tid] : 0;
        ps[tid] = lv;
        __syncthreads();
        for (int off = 1; off < 256; off <<= 1) {
            int add = (tid >= off) ? ps[tid - off] : 0;
            __syncthreads();
            ps[tid] += add;
            __syncthreads();
        }
        if (tid < NBKT) {
            const int loff = ps[tid] - lv;
            lcur[tid] = loff;
            delta[tid] = gbase[tid] - loff;
        }
        __syncthreads();

        // (4) place edges into LDS stage, sorted by bucket
        #pragma unroll
        for (int k = 0; k < 16; ++k) {
            if (d[k] >= 0) {
                const int p = atomicAdd(&lcur[d[k] >> 9], 1);
                stage[p] = ((uint)d[k] << 16) | (uint)s[k];
            }
        }
        __syncthreads();

        // (5) linear write-out: slot i -> ebuf[delta[bkt]+i]; consecutive i = consecutive addr
        const int cnt = (NE - e0 < CHUNK) ? (NE - e0) : CHUNK;
        for (int i = tid; i < cnt; i += 256) {
            const uint e = stage[i];
            ebuf[delta[e >> 25] + i] = e;            // bkt = (e>>16)>>9 = e>>25
        }
        return;
    }

    // ---- gemm role: one 64-row stripe; x staged ONCE; Bs LDS per col-tile (round-16 best) ----
    const int g = b - b / 5 - 1;
    if (g >= N_GEMM) return;
    const int bm = g * 64;

    for (int q = tid; q < 64 * 16; q += 256) {
        int r = q >> 4, c16 = q & 15;
        int row = bm + r;
        uint4 o = make_uint4(0u, 0u, 0u, 0u);
        if (row < NN) {
            const float4 a = *(const float4*)&x[(size_t)row * FIN + c16 * 8];
            const float4 c = *(const float4*)&x[(size_t)row * FIN + c16 * 8 + 4];
            o.x = f2bf_u(a.x) | (f2bf_u(a.y) << 16);
            o.y = f2bf_u(a.z) | (f2bf_u(a.w) << 16);
            o.z = f2bf_u(c.x) | (f2bf_u(c.y) << 16);
            o.w = f2bf_u(c.z) | (f2bf_u(c.w) << 16);
        }
        int off = r * 256 + ((c16 * 16) ^ ((r & 7) << 4));
        *(uint4*)((char*)As + off) = o;
    }

    const int wid = tid >> 6, lane = tid & 63;
    const int wr = (wid >> 1) * 32, wc = (wid & 1) * 32;   // 2x2 waves, each 32x32 per ct
    const int lrow = lane & 15;
    const int lk = (lane >> 4) * 16;

    #pragma unroll
    for (int ct = 0; ct < 4; ++ct) {
        if (ct > 0) __syncthreads();
        for (int q = tid; q < 64 * 16; q += 256) {
            int r = q >> 4, c16 = q & 15;
            uint4 v = *(const uint4*)&Wt[(ct * 64 + r) * FIN + c16 * 8];
            int off = r * 256 + ((c16 * 16) ^ ((r & 7) << 4));
            *(uint4*)((char*)Bs + off) = v;
        }
        __syncthreads();

        f32x4 acc[2][2] = {};
        #pragma unroll
        for (int kk = 0; kk < 4; ++kk) {
            bf16x8 a[2], bb[2];
            #pragma unroll
            for (int m = 0; m < 2; ++m) {
                int r = wr + m * 16 + lrow;
                int off = r * 256 + ((kk * 64 + lk) ^ ((r & 7) << 4));
                a[m] = *(bf16x8*)((char*)As + off);
            }
            #pragma unroll
            for (int n = 0; n < 2; ++n) {
                int r = wc + n * 16 + lrow;
                int off = r * 256 + ((kk * 64 + lk) ^ ((r & 7) << 4));
                bb[n] = *(bf16x8*)((char*)Bs + off);
            }
            // SWAPPED operands: lane holds 4 consecutive cols of one row
            #pragma unroll
            for (int m = 0; m < 2; ++m)
                #pragma unroll
                for (int n = 0; n < 2; ++n)
                    acc[m][n] = __builtin_amdgcn_mfma_f32_16x16x32_bf16(bb[n], a[m], acc[m][n], 0, 0, 0);
        }

        #pragma unroll
        for (int m = 0; m < 2; ++m) {
            const int grow = bm + wr + m * 16 + (lane & 15);
            if (grow >= NN) continue;
            #pragma unroll
            for (int n = 0; n < 2; ++n) {
                const int gcolb = ct * 64 + wc + n * 16 + (lane >> 4) * 4;
                const float4 b4 = (gcolb < 128) ? *(const float4*)&bsrc[gcolb]
                                                : *(const float4*)&bdst[gcolb - 128];
                uint lo = f2h_u(acc[m][n][0] + b4.x) | (f2h_u(acc[m][n][1] + b4.y) << 16);
                uint hi = f2h_u(acc[m][n][2] + b4.z) | (f2h_u(acc[m][n][3] + b4.w) << 16);
                *(uint2*)&fsfd[(size_t)grow * 256 + gcolb] = make_uint2(lo, hi);
            }
        }
    }
}

// ---------------- binB: per-bucket rowptr build (LDS) + coalesced nbr ----------------
__global__ __launch_bounds__(256) void binB_k(
    const uint* __restrict__ ebuf, const int* __restrict__ bkbase,
    int* __restrict__ rowptr, ushort* __restrict__ nbr)
{
    __shared__ int cnt_s[512];
    __shared__ int ps[256];
    __shared__ ushort buf[BCAP];
    const int b = blockIdx.x;
    const int tid = threadIdx.x;
    const int node0 = b << 9;
    const int nodes = (node0 + 512 < NN) ? 512 : (NN - node0);
    const int segbase = bkbase[b];
    const int segend  = bkbase[b + 1];
    const int seglen  = segend - segbase;

    cnt_s[tid] = 0;
    cnt_s[tid + 256] = 0;
    __syncthreads();
    for (int i = segbase + tid; i < segend; i += 256)
        atomicAdd(&cnt_s[(int)(ebuf[i] >> 16) - node0], 1);   // LDS atomic
    __syncthreads();

    const int c0 = cnt_s[2 * tid], c1 = cnt_s[2 * tid + 1];
    const int pair = c0 + c1;
    ps[tid] = pair;
    __syncthreads();
    for (int off = 1; off < 256; off <<= 1) {
        int add = (tid >= off) ? ps[tid - off] : 0;
        __syncthreads();
        ps[tid] += add;
        __syncthreads();
    }
    const int ex = ps[tid] - pair;
    __syncthreads();
    cnt_s[2 * tid] = ex;
    cnt_s[2 * tid + 1] = ex + c0;
    if (2 * tid < nodes)     rowptr[node0 + 2 * tid]     = segbase + ex;
    if (2 * tid + 1 < nodes) rowptr[node0 + 2 * tid + 1] = segbase + ex + c0;
    if (b == NBKT - 1 && tid == 0) rowptr[NN] = segend;
    __syncthreads();

    if (seglen <= BCAP) {
        for (int i = segbase + tid; i < segend; i += 256) {
            const uint e = ebuf[i];
            const int d = (int)(e >> 16) - node0;
            const int p = atomicAdd(&cnt_s[d], 1);
            buf[p] = (ushort)(e & 0xffffu);
        }
        __syncthreads();
        for (int i = tid; i < seglen; i += 256)
            nbr[segbase + i] = buf[i];
    } else {
        for (int i = segbase + tid; i < segend; i += 256) {
            const uint e = ebuf[i];
            const int d = (int)(e >> 16) - node0;
            const int p = atomicAdd(&cnt_s[d], 1);
            nbr[segbase + p] = (ushort)(e & 0xffffu);
        }
    }
}

// ---------------- Fused per-node GAT kernel (packed f16, 4 gathers in flight) ----------------
__global__ __launch_bounds__(256) void gat_node_k(
    const __half* __restrict__ fsfd, const __half* __restrict__ attn_h,
    const int* __restrict__ rowptr, const ushort* __restrict__ nbr,
    float* __restrict__ out)
{
    const int node = blockIdx.x * 4 + (threadIdx.x >> 6);
    const int lane = threadIdx.x & 63;
    const int ql = lane & 15;
    const int q  = lane >> 4;

    const uint4 ufd = *(const uint4*)&fsfd[(size_t)node * 256 + 128 + 8 * ql];
    const __half2 fd0 = u2h(ufd.x), fd1 = u2h(ufd.y), fd2 = u2h(ufd.z), fd3 = u2h(ufd.w);
    const uint4 uav = *(const uint4*)&attn_h[8 * ql];
    const __half2 av0 = u2h(uav.x), av1 = u2h(uav.y), av2 = u2h(uav.z), av3 = u2h(uav.w);
    const __half2 k02 = __float2half2_rn(NEG);

    const int beg = rowptr[node];
    const int end = rowptr[node + 1];

    float den = 0.f;
    __half2 acc0 = u2h(0), acc1 = u2h(0), acc2 = u2h(0), acc3 = u2h(0);

    for (int i = beg; i < end; i += 16) {
        #pragma unroll
        for (int j = 0; j < 4; ++j) {
            const int idx = i + 4 * j + q;
            const bool valid = idx < end;
            const int s = nbr[valid ? idx : end - 1];
            const uint4 u = *(const uint4*)&fsfd[(size_t)s * 256 + 8 * ql];
            const __half2 f0 = u2h(u.x), f1 = u2h(u.y), f2 = u2h(u.z), f3 = u2h(u.w);
            __half2 v0 = __hadd2(f0, fd0), v1 = __hadd2(f1, fd1);
            __half2 v2 = __hadd2(f2, fd2), v3 = __hadd2(f3, fd3);
            v0 = hmax2(v0, __hmul2(v0, k02));
            v1 = hmax2(v1, __hmul2(v1, k02));
            v2 = hmax2(v2, __hmul2(v2, k02));
            v3 = hmax2(v3, __hmul2(v3, k02));
            __half2 sch = __hmul2(v0, av0);
            sch = __hfma2(v1, av1, sch);
            sch = __hfma2(v2, av2, sch);
            sch = __hfma2(v3, av3, sch);
            float sc = __low2float(sch) + __high2float(sch);
            sc = dpp_add<DPP_QUAD_XOR1>(sc);
            sc = dpp_add<DPP_QUAD_XOR2>(sc);
            float ex = __expf(sc);
            ex = valid ? ex : 0.f;
            den += ex;
            const __half2 exh = __float2half2_rn(ex);
            acc0 = __hfma2(exh, f0, acc0);
            acc1 = __hfma2(exh, f1, acc1);
            acc2 = __hfma2(exh, f2, acc2);
            acc3 = __hfma2(exh, f3, acc3);
        }
    }

    den += __shfl_xor(den, 16, 64);
    den += __shfl_xor(den, 32, 64);
    uint ua0 = h2u(acc0), ua1 = h2u(acc1), ua2 = h2u(acc2), ua3 = h2u(acc3);
    ua0 = h2u(__hadd2(u2h(ua0), u2h((uint)__shfl_xor((int)ua0, 16, 64))));
    ua1 = h2u(__hadd2(u2h(ua1), u2h((uint)__shfl_xor((int)ua1, 16, 64))));
    ua2 = h2u(__hadd2(u2h(ua2), u2h((uint)__shfl_xor((int)ua2, 16, 64))));
    ua3 = h2u(__hadd2(u2h(ua3), u2h((uint)__shfl_xor((int)ua3, 16, 64))));
    ua0 = h2u(__hadd2(u2h(ua0), u2h((uint)__shfl_xor((int)ua0, 32, 64))));
    ua1 = h2u(__hadd2(u2h(ua1), u2h((uint)__shfl_xor((int)ua1, 32, 64))));
    ua2 = h2u(__hadd2(u2h(ua2), u2h((uint)__shfl_xor((int)ua2, 32, 64))));
    ua3 = h2u(__hadd2(u2h(ua3), u2h((uint)__shfl_xor((int)ua3, 32, 64))));

    if (q == 0) {
        const float inv = (den > 0.f) ? 1.f / den : 0.f;
        float4 o0, o1;
        o0.x = fmaxf(__low2float(u2h(ua0))  * inv, 0.f);
        o0.y = fmaxf(__high2float(u2h(ua0)) * inv, 0.f);
        o0.z = fmaxf(__low2float(u2h(ua1))  * inv, 0.f);
        o0.w = fmaxf(__high2float(u2h(ua1)) * inv, 0.f);
        o1.x = fmaxf(__low2float(u2h(ua2))  * inv, 0.f);
        o1.y = fmaxf(__high2float(u2h(ua2)) * inv, 0.f);
        o1.z = fmaxf(__low2float(u2h(ua3))  * inv, 0.f);
        o1.w = fmaxf(__high2float(u2h(ua3)) * inv, 0.f);
        *(float4*)&out[(size_t)node * FOUT + 8 * ql] = o0;
        *(float4*)&out[(size_t)node * FOUT + 8 * ql + 4] = o1;
    }
}

extern "C" void kernel_launch(void* const* d_in, const int* in_sizes, int n_in,
                              void* d_out, int out_size, void* d_ws, size_t ws_size,
                              hipStream_t stream)
{
    const float* x    = (const float*)d_in[0];
    const int*   src  = (const int*)d_in[1];
    const int*   dst  = (const int*)d_in[2];
    const float* Wsrc = (const float*)d_in[3];
    const float* bsrc = (const float*)d_in[4];
    const float* Wdst = (const float*)d_in[5];
    const float* bdst = (const float*)d_in[6];
    const float* attn = (const float*)d_in[7];
    float* out = (float*)d_out;

    ushort* Wt      = (ushort*)d_ws;                      // 256*128 bf16
    __half* fsfd    = (__half*)(Wt + 256 * FIN);          // NN*256 f16
    int* chunk_hist = (int*)(fsfd + (size_t)NN * 256);    // NCHUNK*NBKT
    int* bkbase     = chunk_hist + NCHUNK * NBKT;         // NBKT+1
    int* rowptr     = bkbase + NBKT + 1;                  // NN+1
    uint* ebuf      = (uint*)(rowptr + NN + 1);           // NE packed (d<<16)|s
    ushort* nbr     = (ushort*)(ebuf + NE);               // NE u16
    __half* attn_h  = (__half*)(nbr + NE);                // 128 f16

    hist_wt_k<<<NCHUNK + NB_W, 256, 0, stream>>>(dst, chunk_hist, Wsrc, Wdst, Wt, attn, attn_h);
    gemm_scatter_k<<<GB_GRID, 256, 0, stream>>>(x, Wt, bsrc, bdst, fsfd,
                                                dst, src, chunk_hist, bkbase, ebuf);
    binB_k<<<NBKT, 256, 0, stream>>>(ebuf, bkbase, rowptr, nbr);
    gat_node_k<<<(NN + 3) / 4, 256, 0, stream>>>(fsfd, attn_h, rowptr, nbr, out);
}